// Round 18
// baseline (362.836 us; speedup 1.0000x reference)
//
#include <hip/hip_runtime.h>
#include <hip/hip_bf16.h>
#include <math.h>

#define MBLK    64
#define CHUNK   4096                  // one k-chunk: [rowhi(4)][kpart(4)][rowlo(16)][16B]
#define H0_OFF  65536                 // act: 16 chunks; h0: 1 chunk at 65536
#define LDSB    (H0_OFF + CHUNK)      // 69632 (2 blocks/CU)
#define INV2PI  0.15915494309189535f

// packed bf16 weights (ushort elems) in d_ws — all PRE-SCALED by 1/2pi
// hidden layers: [nb(8)][ks(KC)][nf(4)][lane(64)][j(8)]
// output wo:     [half(2)][ks(8)][lane(64)][j(8)]  (n=lane&15, only n<2 nonzero)
// then f32 pre-scaled biases at ushort index NPACK: [b1 512][b2 512][bs1 512][bs2 512][bo 2]
#define OFF_W1  0
#define OFF_W2  16384
#define OFF_WS1 (16384+262144)           // 278528
#define OFF_WS2 (278528+278528)          // 557056
#define OFF_WO  (557056+262144)          // 819200
#define NPACK   (819200+8192)            // 827392
#define NBIAS   2050
#define NTOT    (NPACK + NBIAS)

typedef __attribute__((ext_vector_type(8))) short bf16x8;
typedef __attribute__((ext_vector_type(4))) float f32x4;

struct ResArr { int r[10]; };

__device__ __forceinline__ unsigned short f2bf(float f) {
    unsigned u = __float_as_uint(f);
    u += 0x7FFFu + ((u >> 16) & 1u);       // RNE
    return (unsigned short)(u >> 16);
}
__device__ __forceinline__ float bf2f(unsigned short h) {
    return __uint_as_float(((unsigned)h) << 16);
}
__device__ __forceinline__ float hwsin(float x) {   // sin(2*pi*x)
    float r;
    asm("v_sin_f32 %0, %1" : "=v"(r) : "v"(x));
    return r;
}
__device__ __forceinline__ unsigned pack_bf16_rne(float a, float b) {
    unsigned ua = __float_as_uint(a);
    unsigned ub = __float_as_uint(b);
    ua += 0x7FFFu + ((ua >> 16) & 1u);
    ub += 0x7FFFu + ((ub >> 16) & 1u);
    return __builtin_amdgcn_perm(ub, ua, 0x07060302u);
}

__global__ void pack_weights(const float* __restrict__ w1, const float* __restrict__ w2,
                             const float* __restrict__ ws1, const float* __restrict__ ws2,
                             const float* __restrict__ wo,
                             const float* __restrict__ b1, const float* __restrict__ b2,
                             const float* __restrict__ bs1, const float* __restrict__ bs2,
                             const float* __restrict__ bo,
                             unsigned short* __restrict__ out)
{
    int i = blockIdx.x * 256 + threadIdx.x;
    if (i >= NTOT) return;
    if (i >= NPACK) {                 // pre-scaled f32 biases
        int j = i - NPACK;
        float b;
        if (j < 512)       b = b1[j];
        else if (j < 1024) b = b2[j - 512];
        else if (j < 1536) b = bs1[j - 1024];
        else if (j < 2048) b = bs2[j - 1536];
        else               b = bo[j - 2048];
        ((float*)(out + NPACK))[j] = b * INV2PI;
        return;
    }
    float v;
    if (i < OFF_WO) {
        int il, KC, K_src, K_valid;
        const float* src;
        if (i < OFF_W2)       { il = i;           KC = 1;  K_src = 22;  K_valid = 22;  src = w1;  }
        else if (i < OFF_WS1) { il = i - OFF_W2;  KC = 16; K_src = 512; K_valid = 512; src = w2;  }
        else if (i < OFF_WS2) { il = i - OFF_WS1; KC = 17; K_src = 534; K_valid = 534; src = ws1; }
        else                  { il = i - OFF_WS2; KC = 16; K_src = 512; K_valid = 512; src = ws2; }
        int blk  = il >> 9, idx = il & 511;
        int lane = idx >> 3, j = idx & 7;
        int nf   = blk & 3;
        int rest = blk >> 2;
        int c    = rest % KC;
        int nb   = rest / KC;
        int n = nb * 64 + nf * 16 + (lane & 15);
        int k = c * 32 + (lane >> 4) * 8 + j;
        v = (k < K_valid) ? src[n * K_src + k] : 0.f;
    } else {
        int j = i - OFF_WO;
        int h = j >> 12, ks = (j >> 9) & 7, lane = (j >> 3) & 63, jj = j & 7;
        int n = lane & 15;
        int k = h * 256 + ks * 32 + (lane >> 4) * 8 + jj;
        v = (n < 2) ? wo[n * 512 + k] : 0.f;
    }
    out[i] = f2bf(v * INV2PI);
}

// One MLP layer, in-place on chunked act. 8 waves; wave owns 64 rows x 64 cols (16x16x32 MFMA).
// Lane-sequential LDS layout: fragment (row r, kpart q) of chunk c at c*4096+(r>>4)*1024+q*256+(r&15)*16.
// Bias rides the C-operand of the FIRST (peeled) MFMA step — no acc init, no epilogue add.
template<int KSTEPS, bool TAIL, bool PREBAR>
__device__ __forceinline__ void mlp_layer(char* sm, const unsigned short* __restrict__ Wl,
                                          const float* __restrict__ bsc,
                                          int wid, int lane)
{
    constexpr int NC = KSTEPS + (TAIL ? 1 : 0);
    const int n0 = wid * 64;
    const int lm = lane & 15;
    const int lk = lane >> 4;
    const int abase = lane << 4;                       // conflict-free read base
    const int wbase = wid*8192 + (lk >> 1)*256 + lm*16 + (lk & 1)*8;

    const unsigned short* up = Wl + (unsigned)(__builtin_amdgcn_readfirstlane(wid) * NC) * 2048;
    const int lo8 = lane << 3;

    f32x4 bias4[4];
    #pragma unroll
    for (int nf = 0; nf < 4; ++nf) {
        const float4 bv = *(const float4*)(bsc + n0 + nf*16 + lk*4);
        bias4[nf][0] = bv.x; bias4[nf][1] = bv.y;
        bias4[nf][2] = bv.z; bias4[nf][3] = bv.w;
    }

    f32x4 acc[4][4];

    // ---- peeled first step (C = bias) ----
    {
        const char* app = (KSTEPS > 0) ? (sm + abase) : (sm + H0_OFF + abase);
        bf16x8 w[4], a[4];
        #pragma unroll
        for (int nf = 0; nf < 4; ++nf)
            w[nf] = *(const bf16x8*)(up + nf*512 + lo8);
        #pragma unroll
        for (int mf = 0; mf < 4; ++mf)
            a[mf] = *(const bf16x8*)(app + mf*1024);
        #pragma unroll
        for (int mf = 0; mf < 4; ++mf)
            #pragma unroll
            for (int nf = 0; nf < 4; ++nf)
                acc[mf][nf] = __builtin_amdgcn_mfma_f32_16x16x32_bf16(w[nf], a[mf], bias4[nf], 0, 0, 0);
        up += 2048;
    }

    const char* ab = sm + abase + CHUNK;
    #pragma unroll 1
    for (int ks = 1; ks < KSTEPS; ++ks) {
        bf16x8 w[4], a[4];
        #pragma unroll
        for (int nf = 0; nf < 4; ++nf)
            w[nf] = *(const bf16x8*)(up + nf*512 + lo8);
        #pragma unroll
        for (int mf = 0; mf < 4; ++mf)
            a[mf] = *(const bf16x8*)(ab + mf*1024);
        #pragma unroll
        for (int mf = 0; mf < 4; ++mf)
            #pragma unroll
            for (int nf = 0; nf < 4; ++nf)
                acc[mf][nf] = __builtin_amdgcn_mfma_f32_16x16x32_bf16(w[nf], a[mf], acc[mf][nf], 0, 0, 0);
        up += 2048;
        ab += CHUNK;
    }
    if (TAIL && KSTEPS > 0) {   // K-tail 32 from h0 chunk (same intra-chunk layout)
        bf16x8 w[4], a[4];
        #pragma unroll
        for (int nf = 0; nf < 4; ++nf)
            w[nf] = *(const bf16x8*)(up + nf*512 + lo8);
        #pragma unroll
        for (int mf = 0; mf < 4; ++mf)
            a[mf] = *(const bf16x8*)(sm + H0_OFF + abase + mf*1024);
        #pragma unroll
        for (int mf = 0; mf < 4; ++mf)
            #pragma unroll
            for (int nf = 0; nf < 4; ++nf)
                acc[mf][nf] = __builtin_amdgcn_mfma_f32_16x16x32_bf16(w[nf], a[mf], acc[mf][nf], 0, 0, 0);
    }

    // ---- PRE-barrier epilogue: sin + RNE pack into registers (no LDS touched) ----
    uint2 pk[4][4];
    #pragma unroll
    for (int nf = 0; nf < 4; ++nf) {
        #pragma unroll
        for (int mf = 0; mf < 4; ++mf) {
            float s0 = hwsin(acc[mf][nf][0]);
            float s1 = hwsin(acc[mf][nf][1]);
            float s2 = hwsin(acc[mf][nf][2]);
            float s3 = hwsin(acc[mf][nf][3]);
            pk[nf][mf].x = pack_bf16_rne(s0, s1);
            pk[nf][mf].y = pack_bf16_rne(s2, s3);
        }
    }

    if (PREBAR) __syncthreads();    // all waves done reading act before overwrite

    // ---- stores: n = n0+nf*16+lk*4+{0..3} -> c=wid*2+(nf>>1), q=(nf&1)*2+(lk>>1), j0=(lk&1)*4 ----
    #pragma unroll
    for (int nf = 0; nf < 4; ++nf)
        #pragma unroll
        for (int mf = 0; mf < 4; ++mf)
            *(uint2*)(sm + wbase + (nf >> 1)*4096 + (nf & 1)*512 + mf*1024) = pk[nf][mf];
    __syncthreads();
}

__global__ __launch_bounds__(512) __attribute__((amdgpu_waves_per_eu(4))) void siren_fused(
    const float* __restrict__ coords, const float* __restrict__ table,
    const unsigned short* __restrict__ Wp,
    float* __restrict__ outp,
    ResArr res)
{
    extern __shared__ char sm[];
    const int tid = threadIdx.x;
    const int pbase = blockIdx.x * MBLK;
    const float* bsc = (const float*)(Wp + NPACK);   // pre-scaled biases

    // ---------------- hash encoding -> h0 chunk (lane-sequential layout) ----------------
    {
        int p  = tid & 63;
        int lg = tid >> 6;
        float2 cc = ((const float2*)coords)[pbase + p];
        const int hb = H0_OFF + ((p >> 4) << 10) + ((p & 15) << 4);  // row base
        #pragma unroll
        for (int li = 0; li < 2; ++li) {
            int l = lg + 8 * li;
            if (l < 10) {
                float R  = (float)res.r[l];
                float fx = cc.x * R, fy = cc.y * R;
                float x0 = floorf(fx), y0 = floorf(fy);
                float wx = fx - x0,  wy = fy - y0;
                unsigned xi = (unsigned)x0, yi = (unsigned)y0;
                unsigned yp  = yi * 2654435761u;
                unsigned yp1 = (yi + 1u) * 2654435761u;
                unsigned h00 = (xi        ^ yp ) & 4095u;
                unsigned h10 = ((xi + 1u) ^ yp ) & 4095u;
                unsigned h01 = (xi        ^ yp1) & 4095u;
                unsigned h11 = ((xi + 1u) ^ yp1) & 4095u;
                const float2* tl = (const float2*)(table + l * 8192);
                float2 f00 = tl[h00], f10 = tl[h10], f01 = tl[h01], f11 = tl[h11];
                float a0 = f00.x + (f10.x - f00.x) * wx;
                float a1 = f01.x + (f11.x - f01.x) * wx;
                float g0 = a0 + (a1 - a0) * wy;
                float c0 = f00.y + (f10.y - f00.y) * wx;
                float c1 = f01.y + (f11.y - f01.y) * wx;
                float g1 = c0 + (c1 - c0) * wy;
                unsigned pkv = (unsigned)f2bf(g0) | ((unsigned)f2bf(g1) << 16);
                // k=2l,2l+1 -> q=l>>2, byte (l&3)*4
                *(unsigned*)(sm + hb + ((l >> 2) << 8) + ((l & 3) << 2)) = pkv;
            }
        }
        if (lg == 2) {   // coords -> k=20,21: q=2, byte 8
            unsigned pkv = (unsigned)f2bf(cc.x) | ((unsigned)f2bf(cc.y) << 16);
            *(unsigned*)(sm + hb + 512 + 8) = pkv;
        }
        if (lg == 3) {   // zero pad k=22..31: q=2 byte 12 (4B) + q=3 (16B)
            *(unsigned*)(sm + hb + 512 + 12) = 0u;
            uint4 z = {0u, 0u, 0u, 0u};
            *(uint4*)(sm + hb + 768) = z;
        }
    }
    __syncthreads();

    const int wid  = tid >> 6;
    const int lane = tid & 63;

    mlp_layer<0,  true,  false>(sm, Wp + OFF_W1,  bsc,        wid, lane);  // h0 -> act
    mlp_layer<16, false, true >(sm, Wp + OFF_W2,  bsc + 512,  wid, lane);  // act -> act
    mlp_layer<16, true,  true >(sm, Wp + OFF_WS1, bsc + 1024, wid, lane);  // [act|h0] -> act
    mlp_layer<16, false, true >(sm, Wp + OFF_WS2, bsc + 1536, wid, lane);  // act -> act

    // ---------------- output layer: 512 -> 2 via MFMA split-K ----------------
    {
        const int lm = lane & 15;
        const int lk = lane >> 4;
        const int h  = __builtin_amdgcn_readfirstlane(wid) >> 2;
        // row = (wid&3)*16 + lm, kpart lk, chunks 8h..8h+7
        const int rbase = h*32768 + ((wid & 3) << 10) + (lane << 4);
        const unsigned short* uo = Wp + OFF_WO + h*4096;
        const int lo8 = lane << 3;

        f32x4 acc = {0.f, 0.f, 0.f, 0.f};
        #pragma unroll
        for (int ks = 0; ks < 8; ++ks) {
            bf16x8 w = *(const bf16x8*)(uo + ks*512 + lo8);
            bf16x8 a = *(const bf16x8*)(sm + rbase + ks*CHUNK);
            acc = __builtin_amdgcn_mfma_f32_16x16x32_bf16(w, a, acc, 0, 0, 0);
        }
        __syncthreads();   // act reads done; h0 area reusable for partials
        if (lk == 0) {
            float2 part; part.x = acc[0]; part.y = acc[1];
            *(float2*)(sm + H0_OFF + (h*64 + (wid & 3)*16 + lm)*8) = part;
        }
    }
    __syncthreads();
    if (tid < 64) {
        float2 p0 = *(const float2*)(sm + H0_OFF + tid*8);
        float2 p1 = *(const float2*)(sm + H0_OFF + 512 + tid*8);
        float2 bb = *(const float2*)(bsc + 2048);
        float2 o;
        o.x = hwsin(p0.x + p1.x + bb.x);
        o.y = hwsin(p0.y + p1.y + bb.y);
        ((float2*)outp)[pbase + tid] = o;
    }
}

extern "C" void kernel_launch(void* const* d_in, const int* in_sizes, int n_in,
                              void* d_out, int out_size, void* d_ws, size_t ws_size,
                              hipStream_t stream)
{
    const float* coords = (const float*)d_in[0];
    const float* table  = (const float*)d_in[1];
    const float* w1  = (const float*)d_in[2];
    const float* b1  = (const float*)d_in[3];
    const float* w2  = (const float*)d_in[4];
    const float* b2  = (const float*)d_in[5];
    const float* ws1 = (const float*)d_in[6];
    const float* bs1 = (const float*)d_in[7];
    const float* ws2 = (const float*)d_in[8];
    const float* bs2 = (const float*)d_in[9];
    const float* wo  = (const float*)d_in[10];
    const float* bo  = (const float*)d_in[11];

    unsigned short* Wp = (unsigned short*)d_ws;
    float* outp = (float*)d_out;

    ResArr res;
    double bb = exp((log(320.0) - log(16.0)) / 9.0);
    for (int l = 0; l < 10; ++l) res.r[l] = (int)floor(16.0 * pow(bb, (double)l));

    (void)hipFuncSetAttribute((const void*)siren_fused,
                              hipFuncAttributeMaxDynamicSharedMemorySize, LDSB);

    int N = in_sizes[0] / 2;      // 262144

    pack_weights<<<(NTOT + 255) / 256, 256, 0, stream>>>(w1, w2, ws1, ws2, wo,
                                                         b1, b2, bs1, bs2, bo, Wp);
    siren_fused<<<N / MBLK, 512, LDSB, stream>>>(coords, table, Wp, outp, res);
}

// Round 19
// 361.252 us; speedup vs baseline: 1.0044x; 1.0044x over previous
//
#include <hip/hip_runtime.h>
#include <hip/hip_bf16.h>
#include <math.h>

#define MBLK    64
#define CHUNK   4096                  // one k-chunk: [rowhi(4)][kpart(4)][rowlo(16)][16B]
#define H0_OFF  65536                 // act: 16 chunks; h0: 1 chunk at 65536
#define LDSB    (H0_OFF + CHUNK)      // 69632 (2 blocks/CU)
#define INV2PI  0.15915494309189535f

// packed bf16 weights (ushort elems) in d_ws — all PRE-SCALED by 1/2pi
// hidden layers: [nb(8)][ks(KC)][nf(4)][lane(64)][j(8)]
// output wo:     [half(2)][ks(8)][lane(64)][j(8)]  (n=lane&15, only n<2 nonzero)
// then f32 pre-scaled biases at ushort index NPACK: [b1 512][b2 512][bs1 512][bs2 512][bo 2]
#define OFF_W1  0
#define OFF_W2  16384
#define OFF_WS1 (16384+262144)           // 278528
#define OFF_WS2 (278528+278528)          // 557056
#define OFF_WO  (557056+262144)          // 819200
#define NPACK   (819200+8192)            // 827392
#define NBIAS   2050
#define NTOT    (NPACK + NBIAS)

typedef __attribute__((ext_vector_type(8))) short bf16x8;
typedef __attribute__((ext_vector_type(4))) float f32x4;

struct ResArr { int r[10]; };

__device__ __forceinline__ unsigned short f2bf(float f) {
    unsigned u = __float_as_uint(f);
    u += 0x7FFFu + ((u >> 16) & 1u);       // RNE
    return (unsigned short)(u >> 16);
}
__device__ __forceinline__ float bf2f(unsigned short h) {
    return __uint_as_float(((unsigned)h) << 16);
}
__device__ __forceinline__ float hwsin(float x) {   // sin(2*pi*x)
    float r;
    asm("v_sin_f32 %0, %1" : "=v"(r) : "v"(x));
    return r;
}
__device__ __forceinline__ unsigned pack_bf16_rne(float a, float b) {
    unsigned ua = __float_as_uint(a);
    unsigned ub = __float_as_uint(b);
    ua += 0x7FFFu + ((ua >> 16) & 1u);
    ub += 0x7FFFu + ((ub >> 16) & 1u);
    return __builtin_amdgcn_perm(ub, ua, 0x07060302u);
}

__global__ void pack_weights(const float* __restrict__ w1, const float* __restrict__ w2,
                             const float* __restrict__ ws1, const float* __restrict__ ws2,
                             const float* __restrict__ wo,
                             const float* __restrict__ b1, const float* __restrict__ b2,
                             const float* __restrict__ bs1, const float* __restrict__ bs2,
                             const float* __restrict__ bo,
                             unsigned short* __restrict__ out)
{
    int i = blockIdx.x * 256 + threadIdx.x;
    if (i >= NTOT) return;
    if (i >= NPACK) {                 // pre-scaled f32 biases
        int j = i - NPACK;
        float b;
        if (j < 512)       b = b1[j];
        else if (j < 1024) b = b2[j - 512];
        else if (j < 1536) b = bs1[j - 1024];
        else if (j < 2048) b = bs2[j - 1536];
        else               b = bo[j - 2048];
        ((float*)(out + NPACK))[j] = b * INV2PI;
        return;
    }
    float v;
    if (i < OFF_WO) {
        int il, KC, K_src, K_valid;
        const float* src;
        if (i < OFF_W2)       { il = i;           KC = 1;  K_src = 22;  K_valid = 22;  src = w1;  }
        else if (i < OFF_WS1) { il = i - OFF_W2;  KC = 16; K_src = 512; K_valid = 512; src = w2;  }
        else if (i < OFF_WS2) { il = i - OFF_WS1; KC = 17; K_src = 534; K_valid = 534; src = ws1; }
        else                  { il = i - OFF_WS2; KC = 16; K_src = 512; K_valid = 512; src = ws2; }
        int blk  = il >> 9, idx = il & 511;
        int lane = idx >> 3, j = idx & 7;
        int nf   = blk & 3;
        int rest = blk >> 2;
        int c    = rest % KC;
        int nb   = rest / KC;
        int n = nb * 64 + nf * 16 + (lane & 15);
        int k = c * 32 + (lane >> 4) * 8 + j;
        v = (k < K_valid) ? src[n * K_src + k] : 0.f;
    } else {
        int j = i - OFF_WO;
        int h = j >> 12, ks = (j >> 9) & 7, lane = (j >> 3) & 63, jj = j & 7;
        int n = lane & 15;
        int k = h * 256 + ks * 32 + (lane >> 4) * 8 + jj;
        v = (n < 2) ? wo[n * 512 + k] : 0.f;
    }
    out[i] = f2bf(v * INV2PI);
}

// One MLP layer, in-place on chunked act. 8 waves; wave owns 64 rows x 64 cols (16x16x32 MFMA).
// Lane-sequential LDS layout: fragment (row r, kpart q) of chunk c at c*4096+(r>>4)*1024+q*256+(r&15)*16.
// Reads: lane*16 + imm. Stores: wbase + imm. Bias folded into acc init.
template<int KSTEPS, bool TAIL, bool PREBAR>
__device__ __forceinline__ void mlp_layer(char* sm, const unsigned short* __restrict__ Wl,
                                          const float* __restrict__ bsc,
                                          int wid, int lane)
{
    constexpr int NC = KSTEPS + (TAIL ? 1 : 0);
    const int n0 = wid * 64;
    const int lm = lane & 15;
    const int lk = lane >> 4;
    const int abase = lane << 4;                       // conflict-free read base
    const int wbase = wid*8192 + (lk >> 1)*256 + lm*16 + (lk & 1)*8;

    const unsigned short* up = Wl + (unsigned)(__builtin_amdgcn_readfirstlane(wid) * NC) * 2048;
    const int lo8 = lane << 3;

    f32x4 acc[4][4];
    #pragma unroll
    for (int nf = 0; nf < 4; ++nf) {
        const float4 bv = *(const float4*)(bsc + n0 + nf*16 + lk*4);
        #pragma unroll
        for (int mf = 0; mf < 4; ++mf) {
            acc[mf][nf][0] = bv.x; acc[mf][nf][1] = bv.y;
            acc[mf][nf][2] = bv.z; acc[mf][nf][3] = bv.w;
        }
    }

    const char* ab = sm + abase;
    #pragma unroll 1
    for (int ks = 0; ks < KSTEPS; ++ks) {
        bf16x8 w[4], a[4];
        #pragma unroll
        for (int nf = 0; nf < 4; ++nf)
            w[nf] = *(const bf16x8*)(up + nf*512 + lo8);
        #pragma unroll
        for (int mf = 0; mf < 4; ++mf)
            a[mf] = *(const bf16x8*)(ab + mf*1024);
        __builtin_amdgcn_s_setprio(1);
        #pragma unroll
        for (int mf = 0; mf < 4; ++mf)
            #pragma unroll
            for (int nf = 0; nf < 4; ++nf)
                acc[mf][nf] = __builtin_amdgcn_mfma_f32_16x16x32_bf16(w[nf], a[mf], acc[mf][nf], 0, 0, 0);
        __builtin_amdgcn_s_setprio(0);
        up += 2048;
        ab += CHUNK;
    }
    if (TAIL) {   // K-tail 32 from h0 chunk (same intra-chunk layout)
        bf16x8 w[4], a[4];
        #pragma unroll
        for (int nf = 0; nf < 4; ++nf)
            w[nf] = *(const bf16x8*)(up + nf*512 + lo8);
        #pragma unroll
        for (int mf = 0; mf < 4; ++mf)
            a[mf] = *(const bf16x8*)(sm + H0_OFF + abase + mf*1024);
        __builtin_amdgcn_s_setprio(1);
        #pragma unroll
        for (int mf = 0; mf < 4; ++mf)
            #pragma unroll
            for (int nf = 0; nf < 4; ++nf)
                acc[mf][nf] = __builtin_amdgcn_mfma_f32_16x16x32_bf16(w[nf], a[mf], acc[mf][nf], 0, 0, 0);
        __builtin_amdgcn_s_setprio(0);
    }

    // ---- PRE-barrier epilogue: sin + RNE pack into registers (no LDS touched) ----
    uint2 pk[4][4];
    #pragma unroll
    for (int nf = 0; nf < 4; ++nf) {
        #pragma unroll
        for (int mf = 0; mf < 4; ++mf) {
            float s0 = hwsin(acc[mf][nf][0]);
            float s1 = hwsin(acc[mf][nf][1]);
            float s2 = hwsin(acc[mf][nf][2]);
            float s3 = hwsin(acc[mf][nf][3]);
            pk[nf][mf].x = pack_bf16_rne(s0, s1);
            pk[nf][mf].y = pack_bf16_rne(s2, s3);
        }
    }

    if (PREBAR) __syncthreads();    // all waves done reading act before overwrite

    // ---- stores: n = n0+nf*16+lk*4+{0..3} -> c=wid*2+(nf>>1), q=(nf&1)*2+(lk>>1), j0=(lk&1)*4 ----
    #pragma unroll
    for (int nf = 0; nf < 4; ++nf)
        #pragma unroll
        for (int mf = 0; mf < 4; ++mf)
            *(uint2*)(sm + wbase + (nf >> 1)*4096 + (nf & 1)*512 + mf*1024) = pk[nf][mf];
    __syncthreads();
}

__global__ __launch_bounds__(512) __attribute__((amdgpu_waves_per_eu(4))) void siren_fused(
    const float* __restrict__ coords, const float* __restrict__ table,
    const unsigned short* __restrict__ Wp,
    float* __restrict__ outp,
    ResArr res)
{
    extern __shared__ char sm[];
    const int tid = threadIdx.x;
    const int pbase = blockIdx.x * MBLK;
    const float* bsc = (const float*)(Wp + NPACK);   // pre-scaled biases

    // ---------------- hash encoding -> h0 chunk (lane-sequential layout) ----------------
    {
        int p  = tid & 63;
        int lg = tid >> 6;
        float2 cc = ((const float2*)coords)[pbase + p];
        const int hb = H0_OFF + ((p >> 4) << 10) + ((p & 15) << 4);  // row base
        #pragma unroll
        for (int li = 0; li < 2; ++li) {
            int l = lg + 8 * li;
            if (l < 10) {
                float R  = (float)res.r[l];
                float fx = cc.x * R, fy = cc.y * R;
                float x0 = floorf(fx), y0 = floorf(fy);
                float wx = fx - x0,  wy = fy - y0;
                unsigned xi = (unsigned)x0, yi = (unsigned)y0;
                unsigned yp  = yi * 2654435761u;
                unsigned yp1 = (yi + 1u) * 2654435761u;
                unsigned h00 = (xi        ^ yp ) & 4095u;
                unsigned h10 = ((xi + 1u) ^ yp ) & 4095u;
                unsigned h01 = (xi        ^ yp1) & 4095u;
                unsigned h11 = ((xi + 1u) ^ yp1) & 4095u;
                const float2* tl = (const float2*)(table + l * 8192);
                float2 f00 = tl[h00], f10 = tl[h10], f01 = tl[h01], f11 = tl[h11];
                float a0 = f00.x + (f10.x - f00.x) * wx;
                float a1 = f01.x + (f11.x - f01.x) * wx;
                float g0 = a0 + (a1 - a0) * wy;
                float c0 = f00.y + (f10.y - f00.y) * wx;
                float c1 = f01.y + (f11.y - f01.y) * wx;
                float g1 = c0 + (c1 - c0) * wy;
                unsigned pkv = (unsigned)f2bf(g0) | ((unsigned)f2bf(g1) << 16);
                // k=2l,2l+1 -> q=l>>2, byte (l&3)*4
                *(unsigned*)(sm + hb + ((l >> 2) << 8) + ((l & 3) << 2)) = pkv;
            }
        }
        if (lg == 2) {   // coords -> k=20,21: q=2, byte 8
            unsigned pkv = (unsigned)f2bf(cc.x) | ((unsigned)f2bf(cc.y) << 16);
            *(unsigned*)(sm + hb + 512 + 8) = pkv;
        }
        if (lg == 3) {   // zero pad k=22..31: q=2 byte 12 (4B) + q=3 (16B)
            *(unsigned*)(sm + hb + 512 + 12) = 0u;
            uint4 z = {0u, 0u, 0u, 0u};
            *(uint4*)(sm + hb + 768) = z;
        }
    }
    __syncthreads();

    const int wid  = tid >> 6;
    const int lane = tid & 63;

    mlp_layer<0,  true,  false>(sm, Wp + OFF_W1,  bsc,        wid, lane);  // h0 -> act
    mlp_layer<16, false, true >(sm, Wp + OFF_W2,  bsc + 512,  wid, lane);  // act -> act
    mlp_layer<16, true,  true >(sm, Wp + OFF_WS1, bsc + 1024, wid, lane);  // [act|h0] -> act
    mlp_layer<16, false, true >(sm, Wp + OFF_WS2, bsc + 1536, wid, lane);  // act -> act

    // ---------------- output layer: 512 -> 2 via MFMA split-K ----------------
    {
        const int lm = lane & 15;
        const int lk = lane >> 4;
        const int h  = __builtin_amdgcn_readfirstlane(wid) >> 2;
        // row = (wid&3)*16 + lm, kpart lk, chunks 8h..8h+7
        const int rbase = h*32768 + ((wid & 3) << 10) + (lane << 4);
        const unsigned short* uo = Wp + OFF_WO + h*4096;
        const int lo8 = lane << 3;

        f32x4 acc = {0.f, 0.f, 0.f, 0.f};
        #pragma unroll
        for (int ks = 0; ks < 8; ++ks) {
            bf16x8 w = *(const bf16x8*)(uo + ks*512 + lo8);
            bf16x8 a = *(const bf16x8*)(sm + rbase + ks*CHUNK);
            acc = __builtin_amdgcn_mfma_f32_16x16x32_bf16(w, a, acc, 0, 0, 0);
        }
        __syncthreads();   // act reads done; h0 area reusable for partials
        if (lk == 0) {
            float2 part; part.x = acc[0]; part.y = acc[1];
            *(float2*)(sm + H0_OFF + (h*64 + (wid & 3)*16 + lm)*8) = part;
        }
    }
    __syncthreads();
    if (tid < 64) {
        float2 p0 = *(const float2*)(sm + H0_OFF + tid*8);
        float2 p1 = *(const float2*)(sm + H0_OFF + 512 + tid*8);
        float2 bb = *(const float2*)(bsc + 2048);
        float2 o;
        o.x = hwsin(p0.x + p1.x + bb.x);
        o.y = hwsin(p0.y + p1.y + bb.y);
        ((float2*)outp)[pbase + tid] = o;
    }
}

extern "C" void kernel_launch(void* const* d_in, const int* in_sizes, int n_in,
                              void* d_out, int out_size, void* d_ws, size_t ws_size,
                              hipStream_t stream)
{
    const float* coords = (const float*)d_in[0];
    const float* table  = (const float*)d_in[1];
    const float* w1  = (const float*)d_in[2];
    const float* b1  = (const float*)d_in[3];
    const float* w2  = (const float*)d_in[4];
    const float* b2  = (const float*)d_in[5];
    const float* ws1 = (const float*)d_in[6];
    const float* bs1 = (const float*)d_in[7];
    const float* ws2 = (const float*)d_in[8];
    const float* bs2 = (const float*)d_in[9];
    const float* wo  = (const float*)d_in[10];
    const float* bo  = (const float*)d_in[11];

    unsigned short* Wp = (unsigned short*)d_ws;
    float* outp = (float*)d_out;

    ResArr res;
    double bb = exp((log(320.0) - log(16.0)) / 9.0);
    for (int l = 0; l < 10; ++l) res.r[l] = (int)floor(16.0 * pow(bb, (double)l));

    (void)hipFuncSetAttribute((const void*)siren_fused,
                              hipFuncAttributeMaxDynamicSharedMemorySize, LDSB);

    int N = in_sizes[0] / 2;      // 262144

    pack_weights<<<(NTOT + 255) / 256, 256, 0, stream>>>(w1, w2, ws1, ws2, wo,
                                                         b1, b2, bs1, bs2, bo, Wp);
    siren_fused<<<N / MBLK, 512, LDSB, stream>>>(coords, table, Wp, outp, res);
}